// Round 1
// baseline (11770.802 us; speedup 1.0000x reference)
//
#include <hip/hip_runtime.h>

#define AS1 __attribute__((address_space(1)))
#define AS3 __attribute__((address_space(3)))

typedef unsigned short u16;
typedef __attribute__((ext_vector_type(8))) unsigned short u16x8;
typedef __attribute__((ext_vector_type(8))) __bf16 bf16x8;
typedef __attribute__((ext_vector_type(4))) float f32x4;

// problem dims
#define TT 256
#define BB 64
#define IN_DIM 2048
#define HH 1024
#define GG 4096    // 4*H
#define MM 16384   // T*B

__device__ __forceinline__ u16 f2bf(float f) {
  unsigned u = __builtin_bit_cast(unsigned, f);
  return (u16)((u + 0x7fffu + ((u >> 16) & 1u)) >> 16);  // RNE
}
__device__ __forceinline__ float bf2f(u16 h) {
  unsigned u = ((unsigned)h) << 16;
  return __builtin_bit_cast(float, u);
}
__device__ __forceinline__ f32x4 mfma16(u16x8 a, u16x8 b, f32x4 c) {
  return __builtin_amdgcn_mfma_f32_16x16x32_bf16(
      __builtin_bit_cast(bf16x8, a), __builtin_bit_cast(bf16x8, b), c, 0, 0, 0);
}
__device__ __forceinline__ float sigmoid_fast(float x) {
  float e = __expf(-x);
  return __fdividef(1.f, 1.f + e);
}
__device__ __forceinline__ float tanh_fast(float x) {
  float xx = fmaxf(x, -30.f);
  float e = __expf(-2.f * xx);
  return __fdividef(1.f - e, 1.f + e);
}

// ---------------- prep kernels ----------------
__global__ void cvt_bf16_k(const float* __restrict__ in, u16* __restrict__ out, long n) {
  long i = ((long)blockIdx.x * blockDim.x + threadIdx.x) * 4;
  long stride = (long)gridDim.x * blockDim.x * 4;
  for (; i < n; i += stride) {
    float4 v = *(const float4*)(in + i);
    ushort4 o = { f2bf(v.x), f2bf(v.y), f2bf(v.z), f2bf(v.w) };
    *(ushort4*)(out + i) = o;
  }
}

__global__ void bias_sum_k(const float* __restrict__ a, const float* __restrict__ b,
                           float* __restrict__ o, int n) {
  int i = blockIdx.x * blockDim.x + threadIdx.x;
  if (i < n) o[i] = a[i] + b[i];
}

// ---------------- input GEMM: C[M][N](bf16) = A[M][K](bf16) · W[N][K]^T + bias ----------
// m97 recipe: 128x128 tile, BK=32, global_load_lds width 16, 4 waves 2x2, 4x4 frags/wave.
__global__ __launch_bounds__(256) void gemm_bt_bias(
    const u16* __restrict__ A, const u16* __restrict__ W,
    const float* __restrict__ bias, u16* __restrict__ C, int N, int K) {
  __shared__ u16 As[128 * 32];
  __shared__ u16 Bs[128 * 32];
  const int tid = threadIdx.x, wave = tid >> 6, lane = tid & 63;
  const size_t m0 = (size_t)blockIdx.x * 128, n0 = (size_t)blockIdx.y * 128;
  const int wm = (wave >> 1) * 64, wn = (wave & 1) * 64;
  const int lr = lane & 15, lq = lane >> 4;
  // staging: chunk c covers rows [c*64, c*64+64); thread -> row wave*16 + lane/4, col (lane&3)*8
  const int srow = wave * 16 + (lane >> 2);
  const int scol = (lane & 3) * 8;
  const u16* Ap = A + (m0 + srow) * K + scol;
  const u16* Wp = W + (n0 + srow) * K + scol;
  u16* AsB0 = &As[(wave * 64) * 8];
  u16* AsB1 = &As[(256 + wave * 64) * 8];
  u16* BsB0 = &Bs[(wave * 64) * 8];
  u16* BsB1 = &Bs[(256 + wave * 64) * 8];

  f32x4 acc[4][4];
#pragma unroll
  for (int i = 0; i < 4; ++i)
#pragma unroll
    for (int j = 0; j < 4; ++j) acc[i][j] = (f32x4){0.f, 0.f, 0.f, 0.f};

  for (int k0 = 0; k0 < K; k0 += 32) {
    __builtin_amdgcn_global_load_lds((AS1 const void*)(Ap + k0), (AS3 void*)AsB0, 16, 0, 0);
    __builtin_amdgcn_global_load_lds((AS1 const void*)(Ap + (size_t)64 * K + k0), (AS3 void*)AsB1, 16, 0, 0);
    __builtin_amdgcn_global_load_lds((AS1 const void*)(Wp + k0), (AS3 void*)BsB0, 16, 0, 0);
    __builtin_amdgcn_global_load_lds((AS1 const void*)(Wp + (size_t)64 * K + k0), (AS3 void*)BsB1, 16, 0, 0);
    __syncthreads();  // compiler drains vmcnt before s_barrier
    u16x8 af[4], bf[4];
#pragma unroll
    for (int i = 0; i < 4; ++i) af[i] = *(const u16x8*)&As[(wm + i * 16 + lr) * 32 + lq * 8];
#pragma unroll
    for (int j = 0; j < 4; ++j) bf[j] = *(const u16x8*)&Bs[(wn + j * 16 + lr) * 32 + lq * 8];
#pragma unroll
    for (int i = 0; i < 4; ++i)
#pragma unroll
      for (int j = 0; j < 4; ++j) acc[i][j] = mfma16(af[i], bf[j], acc[i][j]);
    __syncthreads();
  }
  // epilogue: D row m=(lq*4+r), col n=(lane&15)
#pragma unroll
  for (int i = 0; i < 4; ++i) {
#pragma unroll
    for (int j = 0; j < 4; ++j) {
      int n = wn + j * 16 + lr;
      float bv = bias[n0 + n];
#pragma unroll
      for (int r = 0; r < 4; ++r) {
        int m = wm + i * 16 + lq * 4 + r;
        C[(m0 + m) * N + n0 + n] = f2bf(acc[i][j][r] + bv);
      }
    }
  }
}

// ---------------- persistent recurrence ----------------
__device__ __forceinline__ void grid_barrier(unsigned* bar, unsigned nblk) {
  __syncthreads();
  if (threadIdx.x == 0) {
    __threadfence();  // agent-scope release of this block's h/c stores
    unsigned g = __hip_atomic_load(&bar[1], __ATOMIC_RELAXED, __HIP_MEMORY_SCOPE_AGENT);
    unsigned a = __hip_atomic_fetch_add(&bar[0], 1u, __ATOMIC_ACQ_REL, __HIP_MEMORY_SCOPE_AGENT);
    if (a == nblk - 1) {
      __hip_atomic_store(&bar[0], 0u, __ATOMIC_RELAXED, __HIP_MEMORY_SCOPE_AGENT);
      __hip_atomic_store(&bar[1], g + 1u, __ATOMIC_RELEASE, __HIP_MEMORY_SCOPE_AGENT);
    } else {
      while (__hip_atomic_load(&bar[1], __ATOMIC_ACQUIRE, __HIP_MEMORY_SCOPE_AGENT) == g) {
        __builtin_amdgcn_s_sleep(1);
      }
    }
  }
  __syncthreads();
}

// 64 blocks x 256 thr. Block b owns 16 hidden units (64 gate cols). Wave w owns K-quarter.
// W_hh slice lives in registers (breg, 128 VGPRs/lane). h broadcast via global bf16 ping-pong.
__global__ __launch_bounds__(256, 1) void lstm_rec(
    const u16* __restrict__ Whh,   // [4096][1024] bf16
    const u16* __restrict__ xg,    // [T*B][4096] bf16 (includes biases)
    const float* __restrict__ h0,  // [64][1024] layer slice
    const float* __restrict__ c0,
    u16* __restrict__ hping,       // [2][64][1024] bf16
    u16* __restrict__ ybf,         // layer<2: bf16 y out [T*B][1024], else null
    float* __restrict__ yf32,      // layer==2: fp32 y out, else null
    float* __restrict__ hT, float* __restrict__ cT,
    unsigned* __restrict__ bar) {
  __shared__ float pbuf[4][64][68];  // [wave][gatecol][m], pad 68 for banks + f32x4 align
  const int tid = threadIdx.x, wave = tid >> 6, lane = tid & 63;
  const int j0 = blockIdx.x * 16;
  const int lr = lane & 15, lq = lane >> 4;
  const int kbase = wave * 256;

  // resident weights: breg[gate][kstep], lane lr holds W row (g*1024 + j0 + lr)
  u16x8 breg[4][8];
#pragma unroll
  for (int g = 0; g < 4; ++g) {
    const u16* wrow = Whh + (size_t)(g * 1024 + j0 + lr) * 1024 + kbase + lq * 8;
#pragma unroll
    for (int ks = 0; ks < 8; ++ks) breg[g][ks] = *(const u16x8*)(wrow + ks * 32);
  }
  // c state: pair p = tid + q*256 -> (m = p>>4, jj = p&15)
  float creg[4];
#pragma unroll
  for (int q = 0; q < 4; ++q) {
    int p = tid + q * 256, m = p >> 4, jj = p & 15;
    creg[q] = c0[(size_t)m * 1024 + j0 + jj];
  }
  // init ping buffer 0 with h0 (block's columns)
#pragma unroll
  for (int q = 0; q < 4; ++q) {
    int p = tid + q * 256, m = p >> 4, jj = p & 15;
    hping[(size_t)m * 1024 + j0 + jj] = f2bf(h0[(size_t)m * 1024 + j0 + jj]);
  }
  grid_barrier(bar, 64);

  for (int t = 0; t < TT; ++t) {
    const u16* cur = hping + (size_t)(t & 1) * (BB * HH);
    u16* nxt = hping + (size_t)((t + 1) & 1) * (BB * HH);

    f32x4 acc[4][4];
#pragma unroll
    for (int i = 0; i < 4; ++i)
#pragma unroll
      for (int g = 0; g < 4; ++g) acc[i][g] = (f32x4){0.f, 0.f, 0.f, 0.f};

#pragma unroll
    for (int ks = 0; ks < 8; ++ks) {
      u16x8 afr[4];
#pragma unroll
      for (int i = 0; i < 4; ++i)
        afr[i] = *(const u16x8*)(cur + (size_t)(i * 16 + lr) * 1024 + kbase + ks * 32 + lq * 8);
#pragma unroll
      for (int g = 0; g < 4; ++g)
#pragma unroll
        for (int i = 0; i < 4; ++i) acc[i][g] = mfma16(afr[i], breg[g][ks], acc[i][g]);
    }
    // partials to LDS: pbuf[wave][g*16+lr][i*16+lq*4 .. +4] (f32x4 over m)
#pragma unroll
    for (int i = 0; i < 4; ++i)
#pragma unroll
      for (int g = 0; g < 4; ++g)
        *(f32x4*)&pbuf[wave][g * 16 + lr][i * 16 + lq * 4] = acc[i][g];
    __syncthreads();

#pragma unroll
    for (int q = 0; q < 4; ++q) {
      int p = tid + q * 256, m = p >> 4, jj = p & 15;
      const u16* xr = xg + (size_t)(t * BB + m) * GG + j0 + jj;
      float pre[4];
#pragma unroll
      for (int g = 0; g < 4; ++g) {
        float s = pbuf[0][g * 16 + jj][m] + pbuf[1][g * 16 + jj][m] +
                  pbuf[2][g * 16 + jj][m] + pbuf[3][g * 16 + jj][m];
        pre[g] = s + bf2f(xr[(size_t)g * 1024]);
      }
      float ii = sigmoid_fast(pre[0]);
      float ff = sigmoid_fast(pre[1]);
      float gg = tanh_fast(pre[2]);
      float oo = sigmoid_fast(pre[3]);
      float c = ff * creg[q] + ii * gg;
      creg[q] = c;
      float h = oo * tanh_fast(c);
      nxt[(size_t)m * 1024 + j0 + jj] = f2bf(h);
      size_t yidx = (size_t)(t * BB + m) * 1024 + j0 + jj;
      if (ybf) ybf[yidx] = f2bf(h);
      else yf32[yidx] = h;
      if (t == TT - 1) {
        hT[(size_t)m * 1024 + j0 + jj] = h;
        cT[(size_t)m * 1024 + j0 + jj] = c;
      }
    }
    grid_barrier(bar, 64);  // orders nxt-writes vs next step's cur-reads, and pbuf reuse
  }
}

// ---------------- workspace layout (all 256-aligned) ----------------
#define O_BAR   ((size_t)0)
#define O_BIAS  ((size_t)256)                       // 3*4096 f32
#define O_HP    (O_BIAS + 49152)                    // 2*64*1024 bf16
#define O_XBF   (O_HP + 262144)                     // 16384*2048 bf16
#define O_YBF   (O_XBF + 67108864)                  // 16384*1024 bf16
#define O_XG    (O_YBF + 33554432)                  // 16384*4096 bf16
#define O_WIH0  (O_XG + 134217728)
#define O_WIH1  (O_WIH0 + 16777216)
#define O_WIH2  (O_WIH1 + 8388608)
#define O_WHH0  (O_WIH2 + 8388608)
#define O_WHH1  (O_WHH0 + 8388608)
#define O_WHH2  (O_WHH1 + 8388608)

extern "C" void kernel_launch(void* const* d_in, const int* in_sizes, int n_in,
                              void* d_out, int out_size, void* d_ws, size_t ws_size,
                              hipStream_t stream) {
  const float* x = (const float*)d_in[0];
  const float* h0 = (const float*)d_in[1];
  const float* c0 = (const float*)d_in[2];
  char* ws = (char*)d_ws;
  unsigned* bar = (unsigned*)(ws + O_BAR);
  float* bias = (float*)(ws + O_BIAS);
  u16* hping = (u16*)(ws + O_HP);
  u16* xbf = (u16*)(ws + O_XBF);
  u16* ybf = (u16*)(ws + O_YBF);
  u16* xgb = (u16*)(ws + O_XG);
  u16* wih[3] = { (u16*)(ws + O_WIH0), (u16*)(ws + O_WIH1), (u16*)(ws + O_WIH2) };
  u16* whh[3] = { (u16*)(ws + O_WHH0), (u16*)(ws + O_WHH1), (u16*)(ws + O_WHH2) };
  float* youtf = (float*)d_out;
  float* hTo = (float*)d_out + (size_t)TT * BB * HH;
  float* cTo = hTo + 3 * BB * HH;

  hipMemsetAsync(bar, 0, 256, stream);
  cvt_bf16_k<<<4096, 256, 0, stream>>>(x, xbf, (long)MM * IN_DIM);
  for (int l = 0; l < 3; ++l) {
    long wn = (long)GG * (l == 0 ? IN_DIM : HH);
    cvt_bf16_k<<<2048, 256, 0, stream>>>((const float*)d_in[3 + 4 * l], wih[l], wn);
    cvt_bf16_k<<<2048, 256, 0, stream>>>((const float*)d_in[4 + 4 * l], whh[l], (long)GG * HH);
    bias_sum_k<<<16, 256, 0, stream>>>((const float*)d_in[5 + 4 * l],
                                       (const float*)d_in[6 + 4 * l], bias + l * GG, GG);
  }
  for (int l = 0; l < 3; ++l) {
    int K = l ? HH : IN_DIM;
    const u16* Ain = l ? ybf : xbf;
    gemm_bt_bias<<<dim3(128, 32), 256, 0, stream>>>(Ain, wih[l], bias + l * GG, xgb, GG, K);
    lstm_rec<<<64, 256, 0, stream>>>(whh[l], xgb, h0 + (size_t)l * BB * HH,
                                     c0 + (size_t)l * BB * HH, hping,
                                     (l < 2) ? ybf : nullptr, (l < 2) ? nullptr : youtf,
                                     hTo + (size_t)l * BB * HH, cTo + (size_t)l * BB * HH, bar);
  }
}

// Round 2
// 6169.851 us; speedup vs baseline: 1.9078x; 1.9078x over previous
//
#include <hip/hip_runtime.h>

#define AS1 __attribute__((address_space(1)))
#define AS3 __attribute__((address_space(3)))

typedef unsigned short u16;
typedef unsigned long long u64;
typedef __attribute__((ext_vector_type(8))) unsigned short u16x8;
typedef __attribute__((ext_vector_type(8))) __bf16 bf16x8;
typedef __attribute__((ext_vector_type(4))) float f32x4;

// problem dims
#define TT 256
#define BB 64
#define IN_DIM 2048
#define HH 1024
#define GG 4096    // 4*H
#define MM 16384   // T*B
#define NBLK 192   // 3 layers x 64 blocks

__device__ __forceinline__ u16 f2bf(float f) {
  unsigned u = __builtin_bit_cast(unsigned, f);
  return (u16)((u + 0x7fffu + ((u >> 16) & 1u)) >> 16);  // RNE
}
__device__ __forceinline__ float bf2f(u16 h) {
  unsigned u = ((unsigned)h) << 16;
  return __builtin_bit_cast(float, u);
}
__device__ __forceinline__ f32x4 mfma16(u16x8 a, u16x8 b, f32x4 c) {
  return __builtin_amdgcn_mfma_f32_16x16x32_bf16(
      __builtin_bit_cast(bf16x8, a), __builtin_bit_cast(bf16x8, b), c, 0, 0, 0);
}
__device__ __forceinline__ float sigmoid_fast(float x) {
  float e = __expf(-x);
  return __fdividef(1.f, 1.f + e);
}
__device__ __forceinline__ float tanh_fast(float x) {
  float xx = fmaxf(x, -30.f);
  float e = __expf(-2.f * xx);
  return __fdividef(1.f - e, 1.f + e);
}

// ---------------- prep kernels ----------------
__global__ void cvt_bf16_k(const float* __restrict__ in, u16* __restrict__ out, long n) {
  long i = ((long)blockIdx.x * blockDim.x + threadIdx.x) * 4;
  long stride = (long)gridDim.x * blockDim.x * 4;
  for (; i < n; i += stride) {
    float4 v = *(const float4*)(in + i);
    ushort4 o = { f2bf(v.x), f2bf(v.y), f2bf(v.z), f2bf(v.w) };
    *(ushort4*)(out + i) = o;
  }
}

__global__ void bias_sum_k(const float* __restrict__ a, const float* __restrict__ b,
                           float* __restrict__ o, int n) {
  int i = blockIdx.x * blockDim.x + threadIdx.x;
  if (i < n) o[i] = a[i] + b[i];
}

// ---------------- layer-0 input GEMM ----------------
// C_interleaved[m][j][g] (bf16) = A[M][K] . W[4096][K]^T + bias ; n = g*1024+j
__global__ __launch_bounds__(256) void gemm_bt_bias(
    const u16* __restrict__ A, const u16* __restrict__ W,
    const float* __restrict__ bias, u16* __restrict__ C, int K) {
  __shared__ u16 As[128 * 32];
  __shared__ u16 Bs[128 * 32];
  const int tid = threadIdx.x, wave = tid >> 6, lane = tid & 63;
  const size_t m0 = (size_t)blockIdx.x * 128, n0 = (size_t)blockIdx.y * 128;
  const int wm = (wave >> 1) * 64, wn = (wave & 1) * 64;
  const int lr = lane & 15, lq = lane >> 4;
  const int srow = wave * 16 + (lane >> 2);
  const int scol = (lane & 3) * 8;
  const u16* Ap = A + (m0 + srow) * K + scol;
  const u16* Wp = W + (n0 + srow) * K + scol;
  u16* AsB0 = &As[(wave * 64) * 8];
  u16* AsB1 = &As[(256 + wave * 64) * 8];
  u16* BsB0 = &Bs[(wave * 64) * 8];
  u16* BsB1 = &Bs[(256 + wave * 64) * 8];

  f32x4 acc[4][4];
#pragma unroll
  for (int i = 0; i < 4; ++i)
#pragma unroll
    for (int j = 0; j < 4; ++j) acc[i][j] = (f32x4){0.f, 0.f, 0.f, 0.f};

  for (int k0 = 0; k0 < K; k0 += 32) {
    __builtin_amdgcn_global_load_lds((AS1 const void*)(Ap + k0), (AS3 void*)AsB0, 16, 0, 0);
    __builtin_amdgcn_global_load_lds((AS1 const void*)(Ap + (size_t)64 * K + k0), (AS3 void*)AsB1, 16, 0, 0);
    __builtin_amdgcn_global_load_lds((AS1 const void*)(Wp + k0), (AS3 void*)BsB0, 16, 0, 0);
    __builtin_amdgcn_global_load_lds((AS1 const void*)(Wp + (size_t)64 * K + k0), (AS3 void*)BsB1, 16, 0, 0);
    __syncthreads();
    u16x8 af[4], bfr[4];
#pragma unroll
    for (int i = 0; i < 4; ++i) af[i] = *(const u16x8*)&As[(wm + i * 16 + lr) * 32 + lq * 8];
#pragma unroll
    for (int j = 0; j < 4; ++j) bfr[j] = *(const u16x8*)&Bs[(wn + j * 16 + lr) * 32 + lq * 8];
#pragma unroll
    for (int i = 0; i < 4; ++i)
#pragma unroll
      for (int j = 0; j < 4; ++j) acc[i][j] = mfma16(af[i], bfr[j], acc[i][j]);
    __syncthreads();
  }
#pragma unroll
  for (int i = 0; i < 4; ++i) {
#pragma unroll
    for (int j = 0; j < 4; ++j) {
      int n = (int)n0 + wn + j * 16 + lr;
      float bv = bias[n];
      size_t coff = (size_t)((n & 1023) * 4 + (n >> 10));
#pragma unroll
      for (int r = 0; r < 4; ++r) {
        int m = wm + i * 16 + lq * 4 + r;
        C[(m0 + m) * GG + coff] = f2bf(acc[i][j][r] + bv);
      }
    }
  }
}

// ---------------- grid barrier: relaxed arrive, relaxed poll, one acquire-fence ------
__device__ __forceinline__ void gbar(unsigned* bar) {
  __builtin_amdgcn_s_waitcnt(0);  // drain this wave's vmem (sc1 h-stores acked at coherence pt)
  __syncthreads();                // (compiler also drains all waves before s_barrier)
  if (threadIdx.x == 0) {
    unsigned g = __hip_atomic_load(&bar[1], __ATOMIC_RELAXED, __HIP_MEMORY_SCOPE_AGENT);
    unsigned a = __hip_atomic_fetch_add(&bar[0], 1u, __ATOMIC_RELAXED, __HIP_MEMORY_SCOPE_AGENT);
    if (a == NBLK - 1) {
      __hip_atomic_store(&bar[0], 0u, __ATOMIC_RELAXED, __HIP_MEMORY_SCOPE_AGENT);
      __hip_atomic_store(&bar[1], g + 1u, __ATOMIC_RELAXED, __HIP_MEMORY_SCOPE_AGENT);
    } else {
      int spins = 0;
      while (__hip_atomic_load(&bar[1], __ATOMIC_RELAXED, __HIP_MEMORY_SCOPE_AGENT) == g) {
        __builtin_amdgcn_s_sleep(2);
        if ((++spins & 63) == 0)  // progress insurance if relaxed poll caches
          (void)__hip_atomic_load(&bar[1], __ATOMIC_ACQUIRE, __HIP_MEMORY_SCOPE_AGENT);
      }
    }
  }
  __syncthreads();
  // single L1/L2 invalidate per stage: after this, normal loads see remote sc1 stores
  __builtin_amdgcn_fence(__ATOMIC_ACQUIRE, "agent");
}

// ---------------- pipelined persistent recurrence, all 3 layers ----------------
// 192 blocks x 256 thr. layer = blk/64. Block owns 16 hidden cols (64 gate rows).
// Wave w owns K-quarter. W_hh (+W_ih for layers 1,2) resident in VGPRs.
// h exchange: hbuf[layer][slot t&1][64][1024] bf16; stores sc1 (atomic relaxed agent),
// loads normal (L2-cached) after the per-stage acquire fence.
__global__ __launch_bounds__(256, 1) void lstm_pipe(
    const u16* __restrict__ whh0, const u16* __restrict__ whh1, const u16* __restrict__ whh2,
    const u16* __restrict__ wih1, const u16* __restrict__ wih2,
    const u16* __restrict__ xgi,   // [T*B][1024][4] bf16 interleaved, bias included
    const float* __restrict__ bias,// [3][4096] (b_ih+b_hh)
    const float* __restrict__ h0,  // [3][64][1024]
    const float* __restrict__ c0,
    u16* __restrict__ hbuf,        // [3][2][64][1024] bf16
    float* __restrict__ yout,      // [T*B][1024] fp32 (layer 2)
    float* __restrict__ hTo, float* __restrict__ cTo,  // [3][64][1024]
    unsigned* __restrict__ bar) {
  __shared__ float pbuf[4][64][68];
  const int tid = threadIdx.x, wave = tid >> 6, lane = tid & 63;
  const int layer = blockIdx.x >> 6;
  const int j0 = (blockIdx.x & 63) * 16;
  const int lr = lane & 15, lq = lane >> 4;
  const int kbase = wave * 256;
  const u16* Wh = layer == 0 ? whh0 : (layer == 1 ? whh1 : whh2);
  const u16* Wx = layer == 2 ? wih2 : wih1;

  // resident weights: rows g*1024 + j0 + lr, k-cols kbase + ks*32 + lq*8
  u16x8 breg_h[4][8], breg_x[4][8];
#pragma unroll
  for (int g = 0; g < 4; ++g) {
    const u16* wrow = Wh + (size_t)(g * 1024 + j0 + lr) * 1024 + kbase + lq * 8;
#pragma unroll
    for (int ks = 0; ks < 8; ++ks) breg_h[g][ks] = *(const u16x8*)(wrow + ks * 32);
  }
  if (layer > 0) {
#pragma unroll
    for (int g = 0; g < 4; ++g) {
      const u16* wrow = Wx + (size_t)(g * 1024 + j0 + lr) * 1024 + kbase + lq * 8;
#pragma unroll
      for (int ks = 0; ks < 8; ++ks) breg_x[g][ks] = *(const u16x8*)(wrow + ks * 32);
    }
  }

  // pointwise mapping: thread -> m = tid>>2, j = j0 + (tid&3)*4 + d, d=0..3
  const int m = tid >> 2, jc = (tid & 3) * 4;
  float creg[4], bias_r[4][4];
#pragma unroll
  for (int d = 0; d < 4; ++d)
    creg[d] = c0[(size_t)layer * 65536 + (size_t)m * 1024 + j0 + jc + d];
  if (layer > 0) {
#pragma unroll
    for (int g = 0; g < 4; ++g)
#pragma unroll
      for (int d = 0; d < 4; ++d)
        bias_r[g][d] = bias[(size_t)layer * GG + g * 1024 + j0 + jc + d];
  }
  // init h[-1] = h0 into slot 1
  {
    u64 hp = 0;
#pragma unroll
    for (int d = 0; d < 4; ++d)
      hp |= (u64)f2bf(h0[(size_t)layer * 65536 + (size_t)m * 1024 + j0 + jc + d]) << (16 * d);
    __hip_atomic_store((u64*)(hbuf + (size_t)(layer * 2 + 1) * 65536 + (size_t)m * 1024 + j0 + jc),
                       hp, __ATOMIC_RELAXED, __HIP_MEMORY_SCOPE_AGENT);
  }
  gbar(bar);

  for (int s = 0; s < TT + 2; ++s) {
    const int t = s - layer;
    if (t >= 0 && t < TT) {
      f32x4 acc[4][4];
#pragma unroll
      for (int i = 0; i < 4; ++i)
#pragma unroll
        for (int g = 0; g < 4; ++g) acc[i][g] = (f32x4){0.f, 0.f, 0.f, 0.f};

      const u16* hprev = hbuf + (size_t)(layer * 2 + ((t + 1) & 1)) * 65536;  // own h[t-1]
#pragma unroll
      for (int ks = 0; ks < 8; ++ks) {
        u16x8 ao[4];
#pragma unroll
        for (int i = 0; i < 4; ++i)
          ao[i] = *(const u16x8*)(hprev + (size_t)(i * 16 + lr) * 1024 + kbase + ks * 32 + lq * 8);
#pragma unroll
        for (int g = 0; g < 4; ++g)
#pragma unroll
          for (int i = 0; i < 4; ++i) acc[i][g] = mfma16(ao[i], breg_h[g][ks], acc[i][g]);
      }
      if (layer > 0) {
        const u16* hbel = hbuf + (size_t)((layer - 1) * 2 + (t & 1)) * 65536;  // below h[t]
#pragma unroll
        for (int ks = 0; ks < 8; ++ks) {
          u16x8 ab[4];
#pragma unroll
          for (int i = 0; i < 4; ++i)
            ab[i] = *(const u16x8*)(hbel + (size_t)(i * 16 + lr) * 1024 + kbase + ks * 32 + lq * 8);
#pragma unroll
          for (int g = 0; g < 4; ++g)
#pragma unroll
            for (int i = 0; i < 4; ++i) acc[i][g] = mfma16(ab[i], breg_x[g][ks], acc[i][g]);
        }
      }
      // partials -> LDS: pbuf[wave][g*16 + lr][i*16 + lq*4 + r]
#pragma unroll
      for (int i = 0; i < 4; ++i)
#pragma unroll
        for (int g = 0; g < 4; ++g)
          *(f32x4*)&pbuf[wave][g * 16 + lr][i * 16 + lq * 4] = acc[i][g];
      __syncthreads();

      float pre[4][4];  // [d][g]
#pragma unroll
      for (int g = 0; g < 4; ++g)
#pragma unroll
        for (int d = 0; d < 4; ++d)
          pre[d][g] = pbuf[0][g * 16 + jc + d][m] + pbuf[1][g * 16 + jc + d][m] +
                      pbuf[2][g * 16 + jc + d][m] + pbuf[3][g * 16 + jc + d][m];
      if (layer == 0) {
        const u16* xr = xgi + ((size_t)(t * BB + m)) * GG + (size_t)(j0 + jc) * 4;
        u16x8 xa = *(const u16x8*)xr;
        u16x8 xb = *(const u16x8*)(xr + 8);
#pragma unroll
        for (int d = 0; d < 2; ++d)
#pragma unroll
          for (int g = 0; g < 4; ++g) {
            pre[d][g] += bf2f(xa[d * 4 + g]);
            pre[d + 2][g] += bf2f(xb[d * 4 + g]);
          }
      } else {
#pragma unroll
        for (int d = 0; d < 4; ++d)
#pragma unroll
          for (int g = 0; g < 4; ++g) pre[d][g] += bias_r[g][d];
      }
      float hv[4];
#pragma unroll
      for (int d = 0; d < 4; ++d) {
        float ii = sigmoid_fast(pre[d][0]);
        float ff = sigmoid_fast(pre[d][1]);
        float gg = tanh_fast(pre[d][2]);
        float oo = sigmoid_fast(pre[d][3]);
        float c = ff * creg[d] + ii * gg;
        creg[d] = c;
        hv[d] = oo * tanh_fast(c);
      }
      u64 hp = ((u64)f2bf(hv[0])) | ((u64)f2bf(hv[1]) << 16) |
               ((u64)f2bf(hv[2]) << 32) | ((u64)f2bf(hv[3]) << 48);
      __hip_atomic_store((u64*)(hbuf + (size_t)(layer * 2 + (t & 1)) * 65536 + (size_t)m * 1024 + j0 + jc),
                         hp, __ATOMIC_RELAXED, __HIP_MEMORY_SCOPE_AGENT);
      if (layer == 2) {
        float4 yv = { hv[0], hv[1], hv[2], hv[3] };
        *(float4*)(yout + ((size_t)(t * BB + m)) * 1024 + j0 + jc) = yv;
      }
      if (t == TT - 1) {
        float4 hvv = { hv[0], hv[1], hv[2], hv[3] };
        float4 cvv = { creg[0], creg[1], creg[2], creg[3] };
        *(float4*)(hTo + (size_t)layer * 65536 + (size_t)m * 1024 + j0 + jc) = hvv;
        *(float4*)(cTo + (size_t)layer * 65536 + (size_t)m * 1024 + j0 + jc) = cvv;
      }
    }
    if (s != TT + 1) gbar(bar);
  }
}

// ---------------- workspace layout ----------------
#define O_BAR   ((size_t)0)
#define O_BIAS  ((size_t)256)                        // 3*4096 f32 = 49152
#define O_HB    (O_BIAS + 49152)                     // 3*2*64*1024 bf16 = 786432
#define O_XBF   (O_HB + 786432)                      // 16384*2048 bf16 = 67108864
#define O_XGI   (O_XBF + 67108864)                   // 16384*4096 bf16 = 134217728
#define O_WIH0  (O_XGI + 134217728)                  // 16777216
#define O_WIH1  (O_WIH0 + 16777216)                  // 8388608
#define O_WIH2  (O_WIH1 + 8388608)
#define O_WHH0  (O_WIH2 + 8388608)
#define O_WHH1  (O_WHH0 + 8388608)
#define O_WHH2  (O_WHH1 + 8388608)

extern "C" void kernel_launch(void* const* d_in, const int* in_sizes, int n_in,
                              void* d_out, int out_size, void* d_ws, size_t ws_size,
                              hipStream_t stream) {
  const float* x = (const float*)d_in[0];
  const float* h0 = (const float*)d_in[1];
  const float* c0 = (const float*)d_in[2];
  char* ws = (char*)d_ws;
  unsigned* bar = (unsigned*)(ws + O_BAR);
  float* bias = (float*)(ws + O_BIAS);
  u16* hbuf = (u16*)(ws + O_HB);
  u16* xbf = (u16*)(ws + O_XBF);
  u16* xgi = (u16*)(ws + O_XGI);
  u16* wih[3] = { (u16*)(ws + O_WIH0), (u16*)(ws + O_WIH1), (u16*)(ws + O_WIH2) };
  u16* whh[3] = { (u16*)(ws + O_WHH0), (u16*)(ws + O_WHH1), (u16*)(ws + O_WHH2) };
  float* youtf = (float*)d_out;
  float* hTo = (float*)d_out + (size_t)TT * BB * HH;
  float* cTo = hTo + 3 * BB * HH;

  hipMemsetAsync(bar, 0, 256, stream);
  cvt_bf16_k<<<4096, 256, 0, stream>>>(x, xbf, (long)MM * IN_DIM);
  for (int l = 0; l < 3; ++l) {
    long wn = (long)GG * (l == 0 ? IN_DIM : HH);
    cvt_bf16_k<<<2048, 256, 0, stream>>>((const float*)d_in[3 + 4 * l], wih[l], wn);
    cvt_bf16_k<<<2048, 256, 0, stream>>>((const float*)d_in[4 + 4 * l], whh[l], (long)GG * HH);
    bias_sum_k<<<16, 256, 0, stream>>>((const float*)d_in[5 + 4 * l],
                                       (const float*)d_in[6 + 4 * l], bias + l * GG, GG);
  }
  gemm_bt_bias<<<dim3(128, 32), 256, 0, stream>>>(xbf, wih[0], bias, xgi, IN_DIM);
  lstm_pipe<<<NBLK, 256, 0, stream>>>(whh[0], whh[1], whh[2], wih[1], wih[2],
                                      xgi, bias, h0, c0, hbuf, youtf, hTo, cTo, bar);
}